// Round 3
// baseline (141.368 us; speedup 1.0000x reference)
//
#include <hip/hip_runtime.h>

// Chamfer distance, pred [B,N,3] fp32, gt [B,M,3] fp32 -> scalar.
// d(p,q) = ||p||^2 + ||q||^2 - 2 p.q. Targets pre-transformed, PAIR-PACKED:
// per target pair {(-2x0,-2x1,-2y0,-2y1), (-2z0,-2z1,w0,w1)}, w=||q||^2.
// Inner: per 2 targets per query: 3 v_pk_fma_f32 + 1 v_min3_f32.
// RQ=16 queries/thread so each LDS broadcast read feeds 16 queries
// (halves LDS reads / waitcnts / iterations per pair vs RQ=8).
// Both directions fused in one nn launch; both preps in one launch.

typedef float vf2 __attribute__((ext_vector_type(2)));
typedef float vf4 __attribute__((ext_vector_type(4)));

#define B_SZ   8
#define N_PTS  8192
#define M_PTS  8192

#define BLOCK   256
#define RQ      16     // queries per thread (register-tiled)
#define SPLITS  32     // target splits per direction
#define NT_SLICE (M_PTS / SPLITS)   // 256 targets = 256 vf4 staged per block
#define RED_GRID 128

// merged prep: y==0: gt->Tg, y==1: pred->Tp
// per pair g: T[2g]=(-2x0,-2x1,-2y0,-2y1), T[2g+1]=(-2z0,-2z1,w0,w1)
__global__ __launch_bounds__(BLOCK) void chamfer_prep_pk(
    const float* __restrict__ gt, vf4* __restrict__ Tg,
    const float* __restrict__ pred, vf4* __restrict__ Tp, int npairs)
{
    int g = blockIdx.x * BLOCK + threadIdx.x;
    const float* pts = blockIdx.y ? pred : gt;
    vf4* T = blockIdx.y ? Tp : Tg;
    if (g < npairs) {
        const float* p = pts + 6 * (size_t)g;
        float x0 = p[0], y0 = p[1], z0 = p[2];
        float x1 = p[3], y1 = p[4], z1 = p[5];
        float w0 = fmaf(x0, x0, fmaf(y0, y0, z0 * z0));
        float w1 = fmaf(x1, x1, fmaf(y1, y1, z1 * z1));
        T[2 * (size_t)g]     = (vf4){ -2.f * x0, -2.f * x1, -2.f * y0, -2.f * y1 };
        T[2 * (size_t)g + 1] = (vf4){ -2.f * z0, -2.f * z1, w0, w1 };
    }
}

// merged nn: blockIdx.z = s + SPLITS*dir
//   dir 0: qry=pred, tgt=Tg, min=minP ; dir 1: qry=gt, tgt=Tp, min=minG
__global__ __launch_bounds__(BLOCK, 3) void chamfer_nn_min_pk(
    const float* __restrict__ pred, const vf4* __restrict__ Tg,
    unsigned int* __restrict__ minP,
    const float* __restrict__ gt, const vf4* __restrict__ Tp,
    unsigned int* __restrict__ minG)
{
    __shared__ vf4 tile[NT_SLICE];
    const int qb  = blockIdx.x;              // query block (0..1)
    const int b   = blockIdx.y;              // batch
    const int dir = blockIdx.z / SPLITS;
    const int s   = blockIdx.z % SPLITS;
    const int t   = threadIdx.x;

    const float* qry      = dir ? gt   : pred;
    const vf4* tgt        = dir ? Tp   : Tg;
    unsigned int* minbuf  = dir ? minG : minP;
    const int Nq = 8192, Nt = 8192;          // N_PTS == M_PTS

    // stage slice: NT_SLICE vf4 by BLOCK threads (one each)
    tile[t] = tgt[(size_t)b * Nt + (size_t)s * NT_SLICE + t];

    const int qbase = qb * (BLOCK * RQ);
    const float* qp = qry + ((size_t)b * Nq + qbase) * 3;
    vf2 Px[RQ], Py[RQ], Pz[RQ];
    float mn[RQ];
#pragma unroll
    for (int k = 0; k < RQ; ++k) {
        int qi = k * BLOCK + t;
        float x = qp[3 * qi + 0];
        float y = qp[3 * qi + 1];
        float z = qp[3 * qi + 2];
        Px[k] = (vf2){x, x}; Py[k] = (vf2){y, y}; Pz[k] = (vf2){z, z};
        mn[k] = 3.0e38f;
    }
    __syncthreads();

#pragma unroll 2
    for (int j = 0; j < NT_SLICE; j += 2) {  // 2 targets per step
        vf4 v0 = tile[j];                    // (x0,x1,y0,y1) broadcast
        vf4 v1 = tile[j + 1];                // (z0,z1,w0,w1)
        vf2 X = __builtin_shufflevector(v0, v0, 0, 1);
        vf2 Y = __builtin_shufflevector(v0, v0, 2, 3);
        vf2 Z = __builtin_shufflevector(v1, v1, 0, 1);
        vf2 W = __builtin_shufflevector(v1, v1, 2, 3);
#pragma unroll
        for (int k = 0; k < RQ; ++k) {
            vf2 D;
            asm("v_pk_fma_f32 %0, %1, %2, %3" : "=v"(D) : "v"(X), "v"(Px[k]), "v"(W));
            asm("v_pk_fma_f32 %0, %1, %2, %0" : "+v"(D) : "v"(Y), "v"(Py[k]));
            asm("v_pk_fma_f32 %0, %1, %2, %0" : "+v"(D) : "v"(Z), "v"(Pz[k]));
            float dlo = D.x, dhi = D.y;
            asm("v_min3_f32 %0, %0, %1, %2" : "+v"(mn[k]) : "v"(dlo), "v"(dhi));
        }
    }

#pragma unroll
    for (int k = 0; k < RQ; ++k) {
        int qi = qbase + k * BLOCK + t;
        float px = Px[k].x, py = Py[k].x, pz = Pz[k].x;
        float p2 = fmaf(px, px, fmaf(py, py, pz * pz));
        float d  = fmaxf(mn[k] + p2, 0.0f);
        atomicMin(&minbuf[(size_t)b * Nq + qi], __float_as_uint(d));
    }
}

// out += sum(a)*sa + sum(b)*sb, multi-block, out zero-initialized
__global__ __launch_bounds__(BLOCK) void chamfer_reduce_pk(
    const float* __restrict__ a, int na,
    const float* __restrict__ b, int nb,
    float* __restrict__ out, float sa, float sb)
{
    __shared__ float part[BLOCK / 64];
    float s = 0.f;
    int tid = blockIdx.x * BLOCK + threadIdx.x;
    int stride = gridDim.x * BLOCK;
    const float4* a4 = (const float4*)a;
    for (int i = tid; i < na / 4; i += stride) {
        float4 v = a4[i];
        s += (v.x + v.y + v.z + v.w) * sa;
    }
    const float4* b4 = (const float4*)b;
    for (int i = tid; i < nb / 4; i += stride) {
        float4 v = b4[i];
        s += (v.x + v.y + v.z + v.w) * sb;
    }
    for (int o = 32; o > 0; o >>= 1) s += __shfl_down(s, o, 64);
    int w = threadIdx.x >> 6;
    if ((threadIdx.x & 63) == 0) part[w] = s;
    __syncthreads();
    if (threadIdx.x == 0) {
        float tot = 0.f;
#pragma unroll
        for (int i = 0; i < BLOCK / 64; ++i) tot += part[i];
        atomicAdd(out, tot);
    }
}

extern "C" void kernel_launch(void* const* d_in, const int* in_sizes, int n_in,
                              void* d_out, int out_size, void* d_ws, size_t ws_size,
                              hipStream_t stream) {
    const float* pred = (const float*)d_in[0];   // [B, N, 3]
    const float* gt   = (const float*)d_in[1];   // [B, M, 3]
    float* out = (float*)d_out;

    const int BN = B_SZ * N_PTS;   // 65536
    const int BM = B_SZ * M_PTS;   // 65536

    char* ws = (char*)d_ws;
    vf4*          Tg   = (vf4*)(ws);
    vf4*          Tp   = (vf4*)(ws + (size_t)BM * 16);
    unsigned int* minP = (unsigned int*)(ws + (size_t)(BM + BN) * 16);
    unsigned int* minG = minP + BN;

    hipMemsetAsync(minP, 0x7f, (size_t)(BN + BM) * 4, stream);  // ~3.39e38
    hipMemsetAsync(out, 0, sizeof(float), stream);

    chamfer_prep_pk<<<dim3(BM / 2 / BLOCK, 2), BLOCK, 0, stream>>>(
        gt, Tg, pred, Tp, BM / 2);

    dim3 grid_nn(N_PTS / (BLOCK * RQ), B_SZ, 2 * SPLITS);
    chamfer_nn_min_pk<<<grid_nn, BLOCK, 0, stream>>>(pred, Tg, minP, gt, Tp, minG);

    chamfer_reduce_pk<<<RED_GRID, BLOCK, 0, stream>>>(
        (const float*)minP, BN, (const float*)minG, BM, out,
        1.0f / (float)BN, 1.0f / (float)BM);
}

// Round 4
// 117.113 us; speedup vs baseline: 1.2071x; 1.2071x over previous
//
#include <hip/hip_runtime.h>

// Chamfer distance via bf16 MFMA with hi/lo split (fp32-grade precision).
// d(p,q) = ||p||^2 + ||q||^2 - 2 p.q.
// Targets (A-side, rows): u = -2t split into (uh,ul) bf16; wt=||t||^2 3-split.
// Queries (B-side, cols): q split into (qh,ql) bf16; ones for the wt slots.
// K=16 slots pair up as:
//   k0-2 : uh*qh   k3-5 : uh*ql   k6-8 : ul*qh   k9-11: ul*ql
//   k12-14: (wh,wm,wl)*1          k15  : 0
// => D[t][q] = -2 t.q + ||t||^2 + O(1e-5). Query ||q||^2 hoisted past the min.
// One mfma_f32_32x32x16_bf16 = 1024 pairwise distances (2382 TF vs 157 TF fp32).

typedef short bf16x8 __attribute__((ext_vector_type(8)));
typedef float f32x16 __attribute__((ext_vector_type(16)));

#define B_SZ   8
#define NPTS   8192               // per batch, both point sets
#define TOTAL  (B_SZ * NPTS)      // 65536
#define BLOCK  256
#define SLICE  1024               // targets staged in LDS per block
#define SPLITS (NPTS / SLICE)     // 8
#define TILES  (SLICE / 32)       // 32
#define RED_GRID 128

// round-to-nearest bf16 (half-up via +0x8000 carry), return remainder
__device__ __forceinline__ unsigned short bf16rn(float f, float* rem) {
    unsigned u = __float_as_uint(f);
    unsigned h = (u + 0x8000u) & 0xFFFF0000u;
    *rem = f - __uint_as_float(h);
    return (unsigned short)(h >> 16);
}

// One thread per point; blockIdx.y: 0 = gt, 1 = pred.
// Writes A-form (targets), B-form (queries), and fp32 ||.||^2.
__global__ __launch_bounds__(BLOCK) void chamfer_prep_mfma(
    const float* __restrict__ gt, const float* __restrict__ pred,
    uint4* __restrict__ TgA, uint4* __restrict__ TgB, float* __restrict__ Wg,
    uint4* __restrict__ TpA, uint4* __restrict__ TpB, float* __restrict__ Wp)
{
    int i = blockIdx.x * BLOCK + threadIdx.x;
    const float* src = blockIdx.y ? pred : gt;
    uint4* TA = blockIdx.y ? TpA : TgA;
    uint4* TB = blockIdx.y ? TpB : TgB;
    float* W  = blockIdx.y ? Wp  : Wg;

    float x = src[3 * (size_t)i + 0];
    float y = src[3 * (size_t)i + 1];
    float z = src[3 * (size_t)i + 2];
    float w = fmaf(x, x, fmaf(y, y, z * z));
    W[i] = w;

    // A-form: u = -2*coord
    float ux = -2.f * x, uy = -2.f * y, uz = -2.f * z;
    float rx, ry, rz, dx, dy, dz, rw1, rw2, rw3;
    unsigned short uhx = bf16rn(ux, &rx), uhy = bf16rn(uy, &ry), uhz = bf16rn(uz, &rz);
    unsigned short ulx = bf16rn(rx, &dx), uly = bf16rn(ry, &dy), ulz = bf16rn(rz, &dz);
    unsigned short wh = bf16rn(w, &rw1), wm = bf16rn(rw1, &rw2), wl = bf16rn(rw2, &rw3);
    union { unsigned short s[16]; uint4 v[2]; } A;
    A.s[0] = uhx; A.s[1] = uhy; A.s[2]  = uhz;
    A.s[3] = uhx; A.s[4] = uhy; A.s[5]  = uhz;
    A.s[6] = ulx; A.s[7] = uly; A.s[8]  = ulz;
    A.s[9] = ulx; A.s[10] = uly; A.s[11] = ulz;
    A.s[12] = wh; A.s[13] = wm; A.s[14] = wl; A.s[15] = 0;
    TA[2 * (size_t)i]     = A.v[0];
    TA[2 * (size_t)i + 1] = A.v[1];

    // B-form: raw coords
    float sx, sy, sz, ex, ey, ez;
    unsigned short qhx = bf16rn(x, &sx), qhy = bf16rn(y, &sy), qhz = bf16rn(z, &sz);
    unsigned short qlx = bf16rn(sx, &ex), qly = bf16rn(sy, &ey), qlz = bf16rn(sz, &ez);
    union { unsigned short s[16]; uint4 v[2]; } Bb;
    Bb.s[0] = qhx; Bb.s[1] = qhy; Bb.s[2]  = qhz;
    Bb.s[3] = qlx; Bb.s[4] = qly; Bb.s[5]  = qlz;
    Bb.s[6] = qhx; Bb.s[7] = qhy; Bb.s[8]  = qhz;
    Bb.s[9] = qlx; Bb.s[10] = qly; Bb.s[11] = qlz;
    Bb.s[12] = 0x3F80; Bb.s[13] = 0x3F80; Bb.s[14] = 0x3F80; Bb.s[15] = 0;
    TB[2 * (size_t)i]     = Bb.v[0];
    TB[2 * (size_t)i + 1] = Bb.v[1];
}

// grid: (NPTS/256 qblocks, B, 2*SPLITS). Per block: 4 waves x 64 queries = 256 q,
// SLICE targets staged in LDS (XOR-swizzled for conflict-free ds_read_b128).
// Per wave per tile: 1 ds_read_b128 (A-frag) + 2 MFMA (query sets) + min-trees.
__global__ __launch_bounds__(BLOCK, 3) void chamfer_nn_mfma(
    const uint4* __restrict__ TgA, const uint4* __restrict__ TpB,
    const float* __restrict__ Wp, unsigned* __restrict__ minP,
    const uint4* __restrict__ TpA, const uint4* __restrict__ TgB,
    const float* __restrict__ Wg, unsigned* __restrict__ minG)
{
    __shared__ uint4 tileU[SLICE * 2];        // 32 KiB
    char* tileC = (char*)tileU;

    const int qb  = blockIdx.x;
    const int b   = blockIdx.y;
    const int dir = blockIdx.z >> 3;
    const int s   = blockIdx.z & 7;
    const int t    = threadIdx.x;
    const int lane = t & 63, wid = t >> 6;
    const int col  = lane & 31, hi = lane >> 5;

    const uint4* TA      = dir ? TpA : TgA;
    const uint4* TB      = dir ? TgB : TpB;
    const float* WQ      = dir ? Wg  : Wp;
    unsigned*    minbuf  = dir ? minG : minP;

    // stage slice: SLICE points x 32B, granule g = 2*local_t + half
    const uint4* srcA = TA + ((size_t)b * NPTS + (size_t)s * SLICE) * 2;
    for (int it = 0; it < (SLICE * 2) / BLOCK; ++it) {
        int g = t + it * BLOCK;
        uint4 v = srcA[g];
        int tl = g >> 1, gh = g & 1;
        int off = (tl * 32 + gh * 16) ^ (((tl >> 2) & 7) << 4);
        *(uint4*)(tileC + off) = v;
    }

    // B fragments: this wave's 64 queries (2 sets of 32 cols)
    const int qblk = qb * 256 + wid * 64;    // within batch
    const char* TBc = (const char*)(TB + ((size_t)b * NPTS + qblk) * 2);
    bf16x8 bq0 = *(const bf16x8*)(TBc + (size_t)col * 32 + hi * 16);
    bf16x8 bq1 = *(const bf16x8*)(TBc + (size_t)(col + 32) * 32 + hi * 16);

    f32x16 zacc;
#pragma unroll
    for (int j = 0; j < 16; ++j) zacc[j] = 0.f;

    float m0 = 3.0e38f, m1 = 3.0e38f;
    __syncthreads();

    const int hi16 = hi * 16;
#pragma unroll 2
    for (int tt = 0; tt < TILES; ++tt) {
        int trow = tt * 32 + col;
        int off = (trow * 32 + hi16) ^ (((trow >> 2) & 7) << 4);
        bf16x8 a = *(const bf16x8*)(tileC + off);
        f32x16 d0 = __builtin_amdgcn_mfma_f32_32x32x16_bf16(a, bq0, zacc, 0, 0, 0);
        f32x16 d1 = __builtin_amdgcn_mfma_f32_32x32x16_bf16(a, bq1, zacc, 0, 0, 0);
        float u0 = fminf(fminf(fminf(d0[0], d0[1]), fminf(d0[2], d0[3])),
                         fminf(fminf(d0[4], d0[5]), fminf(d0[6], d0[7])));
        float v0 = fminf(fminf(fminf(d0[8], d0[9]), fminf(d0[10], d0[11])),
                         fminf(fminf(d0[12], d0[13]), fminf(d0[14], d0[15])));
        m0 = fminf(m0, fminf(u0, v0));
        float u1 = fminf(fminf(fminf(d1[0], d1[1]), fminf(d1[2], d1[3])),
                         fminf(fminf(d1[4], d1[5]), fminf(d1[6], d1[7])));
        float v1 = fminf(fminf(fminf(d1[8], d1[9]), fminf(d1[10], d1[11])),
                         fminf(fminf(d1[12], d1[13]), fminf(d1[14], d1[15])));
        m1 = fminf(m1, fminf(u1, v1));
    }

    // combine the two row-halves (lanes l and l+32 hold same query col)
    m0 = fminf(m0, __shfl_xor(m0, 32));
    m1 = fminf(m1, __shfl_xor(m1, 32));
    if (lane < 32) {
        int q0 = b * NPTS + qblk + lane;
        float d0f = fmaxf(m0 + WQ[q0], 0.f);
        atomicMin(&minbuf[q0], __float_as_uint(d0f));
        int q1 = q0 + 32;
        float d1f = fmaxf(m1 + WQ[q1], 0.f);
        atomicMin(&minbuf[q1], __float_as_uint(d1f));
    }
}

// out += sum(a)*sa + sum(b)*sb, multi-block, out zero-initialized
__global__ __launch_bounds__(BLOCK) void chamfer_reduce_mfma(
    const float* __restrict__ a, int na,
    const float* __restrict__ b, int nb,
    float* __restrict__ out, float sa, float sb)
{
    __shared__ float part[BLOCK / 64];
    float s = 0.f;
    int tid = blockIdx.x * BLOCK + threadIdx.x;
    int stride = gridDim.x * BLOCK;
    const float4* a4 = (const float4*)a;
    for (int i = tid; i < na / 4; i += stride) {
        float4 v = a4[i];
        s += (v.x + v.y + v.z + v.w) * sa;
    }
    const float4* b4 = (const float4*)b;
    for (int i = tid; i < nb / 4; i += stride) {
        float4 v = b4[i];
        s += (v.x + v.y + v.z + v.w) * sb;
    }
    for (int o = 32; o > 0; o >>= 1) s += __shfl_down(s, o, 64);
    int w = threadIdx.x >> 6;
    if ((threadIdx.x & 63) == 0) part[w] = s;
    __syncthreads();
    if (threadIdx.x == 0) {
        float tot = 0.f;
#pragma unroll
        for (int i = 0; i < BLOCK / 64; ++i) tot += part[i];
        atomicAdd(out, tot);
    }
}

extern "C" void kernel_launch(void* const* d_in, const int* in_sizes, int n_in,
                              void* d_out, int out_size, void* d_ws, size_t ws_size,
                              hipStream_t stream) {
    const float* pred = (const float*)d_in[0];   // [B, N, 3]
    const float* gt   = (const float*)d_in[1];   // [B, M, 3]
    float* out = (float*)d_out;

    // ws layout: TgA, TpA, TgB, TpB (32B/point each), Wg, Wp, minP, minG
    char* ws = (char*)d_ws;
    uint4* TgA = (uint4*)(ws);
    uint4* TpA = (uint4*)(ws + (size_t)TOTAL * 32);
    uint4* TgB = (uint4*)(ws + (size_t)TOTAL * 64);
    uint4* TpB = (uint4*)(ws + (size_t)TOTAL * 96);
    float* Wg  = (float*)(ws + (size_t)TOTAL * 128);
    float* Wp  = (float*)(ws + (size_t)TOTAL * 128 + (size_t)TOTAL * 4);
    unsigned* minP = (unsigned*)(ws + (size_t)TOTAL * 128 + (size_t)TOTAL * 8);
    unsigned* minG = (unsigned*)(ws + (size_t)TOTAL * 128 + (size_t)TOTAL * 12);

    hipMemsetAsync(minP, 0x7f, (size_t)TOTAL * 8, stream);   // minP+minG ~3.39e38
    hipMemsetAsync(out, 0, sizeof(float), stream);

    chamfer_prep_mfma<<<dim3(TOTAL / BLOCK, 2), BLOCK, 0, stream>>>(
        gt, pred, TgA, TgB, Wg, TpA, TpB, Wp);

    chamfer_nn_mfma<<<dim3(NPTS / 256, B_SZ, 2 * SPLITS), BLOCK, 0, stream>>>(
        TgA, TpB, Wp, minP, TpA, TgB, Wg, minG);

    chamfer_reduce_mfma<<<RED_GRID, BLOCK, 0, stream>>>(
        (const float*)minP, TOTAL, (const float*)minG, TOTAL, out,
        1.0f / (float)TOTAL, 1.0f / (float)TOTAL);
}

// Round 6
// 99.637 us; speedup vs baseline: 1.4188x; 1.1754x over previous
//
#include <hip/hip_runtime.h>

// Chamfer distance via bf16 MFMA with hi/lo split (fp32-grade precision).
// d(p,q) = ||p||^2 + ||q||^2 - 2 p.q.
// A row (target): [uh x3, uh x3, ul x3, ul x3, wh wm wl, 0], u=-2t, w=||t||^2
// B col (query):  [qh x3, ql x3, qh x3, ql x3, 1 1 1, 0]
// => D = -2 t.q + ||t||^2 + O(1e-5); query ||q||^2 added after the min.
// Round-4-proven data path (prep kernel -> global TA/TB/W -> granule-swizzled
// LDS staging -> imm-offset ds_read_b128 A-frags); fused min+reduce epilogue
// (no minbuf/atomicMin/reduce kernel: 3 graph nodes total).

typedef short bf16x8 __attribute__((ext_vector_type(8)));
typedef float f32x16 __attribute__((ext_vector_type(16)));

#define B_SZ   8
#define NPTS   8192
#define TOTAL  (B_SZ * NPTS)     // 65536
#define BLOCK  256
#define QB     256               // queries per block
#define SLICE  1024              // targets per LDS stage
#define NSTAGE (NPTS / SLICE)    // 8
#define TILES  (SLICE / 32)      // 32

// round-to-nearest bf16 (half-up via +0x8000 carry), return remainder
__device__ __forceinline__ unsigned short bf16rn(float f, float* rem) {
    unsigned u = __float_as_uint(f);
    unsigned h = (u + 0x8000u) & 0xFFFF0000u;
    *rem = f - __uint_as_float(h);
    return (unsigned short)(h >> 16);
}

// One thread per point; blockIdx.y: 0 = gt, 1 = pred.  (round-4 exact)
__global__ __launch_bounds__(BLOCK) void chamfer_prep_mfma(
    const float* __restrict__ gt, const float* __restrict__ pred,
    uint4* __restrict__ TgA, uint4* __restrict__ TgB, float* __restrict__ Wg,
    uint4* __restrict__ TpA, uint4* __restrict__ TpB, float* __restrict__ Wp)
{
    int i = blockIdx.x * BLOCK + threadIdx.x;
    const float* src = blockIdx.y ? pred : gt;
    uint4* TA = blockIdx.y ? TpA : TgA;
    uint4* TB = blockIdx.y ? TpB : TgB;
    float* W  = blockIdx.y ? Wp  : Wg;

    float x = src[3 * (size_t)i + 0];
    float y = src[3 * (size_t)i + 1];
    float z = src[3 * (size_t)i + 2];
    float w = fmaf(x, x, fmaf(y, y, z * z));
    W[i] = w;

    float ux = -2.f * x, uy = -2.f * y, uz = -2.f * z;
    float rx, ry, rz, dx, dy, dz, rw1, rw2, rw3;
    unsigned short uhx = bf16rn(ux, &rx), uhy = bf16rn(uy, &ry), uhz = bf16rn(uz, &rz);
    unsigned short ulx = bf16rn(rx, &dx), uly = bf16rn(ry, &dy), ulz = bf16rn(rz, &dz);
    unsigned short wh = bf16rn(w, &rw1), wm = bf16rn(rw1, &rw2), wl = bf16rn(rw2, &rw3);
    union { unsigned short s[16]; uint4 v[2]; } A;
    A.s[0] = uhx; A.s[1] = uhy; A.s[2]  = uhz;
    A.s[3] = uhx; A.s[4] = uhy; A.s[5]  = uhz;
    A.s[6] = ulx; A.s[7] = uly; A.s[8]  = ulz;
    A.s[9] = ulx; A.s[10] = uly; A.s[11] = ulz;
    A.s[12] = wh; A.s[13] = wm; A.s[14] = wl; A.s[15] = 0;
    TA[2 * (size_t)i]     = A.v[0];
    TA[2 * (size_t)i + 1] = A.v[1];

    float sx, sy, sz, ex, ey, ez;
    unsigned short qhx = bf16rn(x, &sx), qhy = bf16rn(y, &sy), qhz = bf16rn(z, &sz);
    unsigned short qlx = bf16rn(sx, &ex), qly = bf16rn(sy, &ey), qlz = bf16rn(sz, &ez);
    union { unsigned short s[16]; uint4 v[2]; } Bb;
    Bb.s[0] = qhx; Bb.s[1] = qhy; Bb.s[2]  = qhz;
    Bb.s[3] = qlx; Bb.s[4] = qly; Bb.s[5]  = qlz;
    Bb.s[6] = qhx; Bb.s[7] = qhy; Bb.s[8]  = qhz;
    Bb.s[9] = qlx; Bb.s[10] = qly; Bb.s[11] = qlz;
    Bb.s[12] = 0x3F80; Bb.s[13] = 0x3F80; Bb.s[14] = 0x3F80; Bb.s[15] = 0;
    TB[2 * (size_t)i]     = Bb.v[0];
    TB[2 * (size_t)i + 1] = Bb.v[1];
}

// m = min(m, d[0..15]) : min3-fusable triples (8 x v_min3_f32 when fused)
__device__ __forceinline__ float minred(f32x16 d, float m) {
    float r0 = fminf(fminf(d[0], d[1]), d[2]);
    float r1 = fminf(fminf(d[3], d[4]), d[5]);
    float r2 = fminf(fminf(d[6], d[7]), d[8]);
    float r3 = fminf(fminf(d[9], d[10]), d[11]);
    float r4 = fminf(fminf(d[12], d[13]), d[14]);
    float s0 = fminf(fminf(r0, r1), r2);
    float s1 = fminf(fminf(r3, r4), d[15]);
    return fminf(fminf(m, s0), s1);
}

// grid (NPTS/QB=32, B_SZ=8, 2 dirs), 256 threads. Each block: 256 queries
// (4 waves x 64), ALL 8192 targets via 8 LDS stages. One atomicAdd per block.
__global__ __launch_bounds__(BLOCK, 2) void chamfer_nn_fused(
    const uint4* __restrict__ TgA, const uint4* __restrict__ TpB,
    const float* __restrict__ Wp,
    const uint4* __restrict__ TpA, const uint4* __restrict__ TgB,
    const float* __restrict__ Wg,
    float* __restrict__ out)
{
    __shared__ uint4 tileU[SLICE * 2];       // 32 KiB A-forms
    __shared__ float psum[4];
    char* tileC = (char*)tileU;

    const int qb = blockIdx.x, b = blockIdx.y, dir = blockIdx.z;
    const int t = threadIdx.x, lane = t & 63, wid = t >> 6;
    const int col = lane & 31, hi = lane >> 5;

    const uint4* TA = dir ? TpA : TgA;
    const uint4* TB = dir ? TgB : TpB;
    const float* WQ = dir ? Wg  : Wp;

    // B fragments from global (round-4 exact): wave covers queries
    // qblk..qblk+63 as two 32-column sets
    const int qblk = qb * QB + wid * 64;
    const char* TBc = (const char*)(TB + ((size_t)b * NPTS + qblk) * 2);
    bf16x8 bq0 = *(const bf16x8*)(TBc + (size_t)col * 32 + hi * 16);
    bf16x8 bq1 = *(const bf16x8*)(TBc + (size_t)(col + 32) * 32 + hi * 16);

    f32x16 zacc;
#pragma unroll
    for (int j = 0; j < 16; ++j) zacc[j] = 0.f;
    float m0 = 3.0e38f, m1 = 3.0e38f;
    // swizzled A-frag base; per-tile offset is the imm tt*1024
    const int abase = (col * 32 + hi * 16) ^ (((col >> 2) & 7) << 4);

    for (int st = 0; st < NSTAGE; ++st) {
        // stage SLICE targets: granule-swizzled copy (round-4 exact)
        const uint4* srcA = TA + ((size_t)b * NPTS + (size_t)st * SLICE) * 2;
#pragma unroll
        for (int it = 0; it < (SLICE * 2) / BLOCK; ++it) {
            int g = t + it * BLOCK;
            uint4 v = srcA[g];
            int tl = g >> 1, gh = g & 1;
            int off = (tl * 32 + gh * 16) ^ (((tl >> 2) & 7) << 4);
            *(uint4*)(tileC + off) = v;
        }
        __syncthreads();

#pragma unroll 2
        for (int tt = 0; tt < TILES; ++tt) {
            bf16x8 a = *(const bf16x8*)(tileC + abase + tt * 1024);
            f32x16 d0 = __builtin_amdgcn_mfma_f32_32x32x16_bf16(a, bq0, zacc, 0, 0, 0);
            m0 = minred(d0, m0);
            f32x16 d1 = __builtin_amdgcn_mfma_f32_32x32x16_bf16(a, bq1, zacc, 0, 0, 0);
            m1 = minred(d1, m1);
        }
        __syncthreads();
    }

    // epilogue: combine row-halves (lanes l, l^32 share query col), add ||q||^2
    m0 = fminf(m0, __shfl_xor(m0, 32));
    m1 = fminf(m1, __shfl_xor(m1, 32));
    // lane<32: m0 is query qblk+lane = this thread's t; lane>=32: m1 is
    // query qblk+32+(lane&31) = this thread's t. (round-4 verified mapping)
    float wq = WQ[(size_t)b * NPTS + qb * QB + t];
    float d = fmaxf((lane < 32 ? m0 : m1) + wq, 0.0f);
    float s = d;
#pragma unroll
    for (int o = 1; o < 64; o <<= 1) s += __shfl_xor(s, o);
    if (lane == 0) psum[wid] = s;
    __syncthreads();
    if (t == 0) {
        float tot = (psum[0] + psum[1]) + (psum[2] + psum[3]);
        atomicAdd(out, tot * (1.0f / (float)TOTAL));
    }
}

extern "C" void kernel_launch(void* const* d_in, const int* in_sizes, int n_in,
                              void* d_out, int out_size, void* d_ws, size_t ws_size,
                              hipStream_t stream) {
    const float* pred = (const float*)d_in[0];   // [B, N, 3]
    const float* gt   = (const float*)d_in[1];   // [B, M, 3]
    float* out = (float*)d_out;

    // ws layout: TgA, TpA, TgB, TpB (32B/point), Wg, Wp
    char* ws = (char*)d_ws;
    uint4* TgA = (uint4*)(ws);
    uint4* TpA = (uint4*)(ws + (size_t)TOTAL * 32);
    uint4* TgB = (uint4*)(ws + (size_t)TOTAL * 64);
    uint4* TpB = (uint4*)(ws + (size_t)TOTAL * 96);
    float* Wg  = (float*)(ws + (size_t)TOTAL * 128);
    float* Wp  = (float*)(ws + (size_t)TOTAL * 128 + (size_t)TOTAL * 4);

    hipMemsetAsync(out, 0, sizeof(float), stream);

    chamfer_prep_mfma<<<dim3(TOTAL / BLOCK, 2), BLOCK, 0, stream>>>(
        gt, pred, TgA, TgB, Wg, TpA, TpB, Wp);

    chamfer_nn_fused<<<dim3(NPTS / QB, B_SZ, 2), BLOCK, 0, stream>>>(
        TgA, TpB, Wp, TpA, TgB, Wg, out);
}